// Round 1
// baseline (68.865 us; speedup 1.0000x reference)
//
#include <hip/hip_runtime.h>
#include <math.h>

#define PLANES   8192   // 16 batches * 512 channels
#define PLANE_SZ 4096   // 64*64
#define CHANS    512

// ---------------------------------------------------------------------------
// Kernel 1: gp[b,c] = mean over the 64x64 plane of map1[b,c]
// One block per (b,c) plane. 256 threads * 4 float4 = 4096 floats.
// ---------------------------------------------------------------------------
__global__ __launch_bounds__(256) void gp_reduce_kernel(
    const float* __restrict__ x1, const float* __restrict__ x2,
    const float* __restrict__ x3, const float* __restrict__ x4,
    float* __restrict__ gp)
{
    const int plane = blockIdx.x;          // b*512 + c
    const int c = plane & (CHANS - 1);
    const int b = plane >> 9;
    const int xi = c >> 7;                 // which of x1..x4
    const float* src = (xi == 0) ? x1 : (xi == 1) ? x2 : (xi == 2) ? x3 : x4;
    src += (size_t)(b * 128 + (c & 127)) * PLANE_SZ;

    const int tid = threadIdx.x;
    const float4* p4 = (const float4*)src;
    float s = 0.f;
    #pragma unroll
    for (int j = 0; j < 4; ++j) {
        float4 v = p4[tid + j * 256];
        s += (v.x + v.y) + (v.z + v.w);
    }
    // wave (64-lane) reduce
    #pragma unroll
    for (int off = 32; off > 0; off >>= 1)
        s += __shfl_down(s, off, 64);

    __shared__ float wsum[4];
    const int lane = tid & 63, wv = tid >> 6;
    if (lane == 0) wsum[wv] = s;
    __syncthreads();
    if (tid == 0) {
        float t = (wsum[0] + wsum[1]) + (wsum[2] + wsum[3]);
        gp[plane] = t * (1.0f / PLANE_SZ);
    }
}

// ---------------------------------------------------------------------------
// Kernel 2: gate[b,c] = sigmoid( lin_b + sum_i lin_w[i] *
//              relu( conv_b[i] + sum_k conv_w[i,k] * gp[b, c + d_i*(k-4)] ) )
// (padding p = 4*d makes all branch outputs length 512, centered taps)
// ---------------------------------------------------------------------------
__global__ __launch_bounds__(256) void gate_kernel(
    const float* __restrict__ gp,
    const float* __restrict__ conv_w, const float* __restrict__ conv_b,
    const float* __restrict__ lin_w,  const float* __restrict__ lin_b,
    float* __restrict__ gate)
{
    const int idx = blockIdx.x * 256 + threadIdx.x;   // b*512 + c
    if (idx >= PLANES) return;
    const int b = idx >> 9, c = idx & (CHANS - 1);
    const float* g = gp + b * CHANS;

    float lin = lin_b[0];
    #pragma unroll
    for (int i = 0; i < 4; ++i) {
        const int d = 1 << i;                 // dilations 1,2,4,8
        float acc = conv_b[i];
        #pragma unroll
        for (int k = 0; k < 9; ++k) {
            const int t = c + d * (k - 4);
            if (t >= 0 && t < CHANS) acc += conv_w[i * 9 + k] * g[t];
        }
        lin += lin_w[i] * fmaxf(acc, 0.f);
    }
    gate[idx] = 1.0f / (1.0f + expf(-lin));
}

// ---------------------------------------------------------------------------
// Kernel 3: out[b,c,:,:] = gate[b,c] * map1[b,c,:,:]
// One block per plane, float4 coalesced.
// ---------------------------------------------------------------------------
__global__ __launch_bounds__(256) void scale_kernel(
    const float* __restrict__ x1, const float* __restrict__ x2,
    const float* __restrict__ x3, const float* __restrict__ x4,
    const float* __restrict__ gate, float* __restrict__ out)
{
    const int plane = blockIdx.x;
    const int c = plane & (CHANS - 1);
    const int b = plane >> 9;
    const int xi = c >> 7;
    const float* src = (xi == 0) ? x1 : (xi == 1) ? x2 : (xi == 2) ? x3 : x4;
    src += (size_t)(b * 128 + (c & 127)) * PLANE_SZ;

    const float gv = gate[plane];
    const float4* p4 = (const float4*)src;
    float4* o4 = (float4*)(out + (size_t)plane * PLANE_SZ);

    const int tid = threadIdx.x;
    #pragma unroll
    for (int j = 0; j < 4; ++j) {
        float4 v = p4[tid + j * 256];
        v.x *= gv; v.y *= gv; v.z *= gv; v.w *= gv;
        o4[tid + j * 256] = v;
    }
}

extern "C" void kernel_launch(void* const* d_in, const int* in_sizes, int n_in,
                              void* d_out, int out_size, void* d_ws, size_t ws_size,
                              hipStream_t stream) {
    const float* x1     = (const float*)d_in[0];
    const float* x2     = (const float*)d_in[1];
    const float* x3     = (const float*)d_in[2];
    const float* x4     = (const float*)d_in[3];
    const float* conv_w = (const float*)d_in[4];
    const float* conv_b = (const float*)d_in[5];
    const float* lin_w  = (const float*)d_in[6];
    const float* lin_b  = (const float*)d_in[7];
    float* out = (float*)d_out;

    float* gp   = (float*)d_ws;            // PLANES floats
    float* gate = gp + PLANES;             // PLANES floats

    gp_reduce_kernel<<<PLANES, 256, 0, stream>>>(x1, x2, x3, x4, gp);
    gate_kernel<<<PLANES / 256, 256, 0, stream>>>(gp, conv_w, conv_b, lin_w, lin_b, gate);
    scale_kernel<<<PLANES, 256, 0, stream>>>(x1, x2, x3, x4, gate, out);
}

// Round 3
// 65.897 us; speedup vs baseline: 1.0450x; 1.0450x over previous
//
#include <hip/hip_runtime.h>
#include <math.h>

#define PLANES   8192   // 16 batches * 512 channels
#define PLANE_SZ 4096   // 64*64
#define CHANS    512

typedef float f32x4 __attribute__((ext_vector_type(4)));

// ---------------------------------------------------------------------------
// Kernel 1: gp[b,c] = mean over the 64x64 plane of map1[b,c]
// One block per (b,c) plane. 256 threads * 4 float4 = 4096 floats.
// ---------------------------------------------------------------------------
__global__ __launch_bounds__(256) void gp_reduce_kernel(
    const float* __restrict__ x1, const float* __restrict__ x2,
    const float* __restrict__ x3, const float* __restrict__ x4,
    float* __restrict__ gp)
{
    const int plane = blockIdx.x;          // b*512 + c
    const int c = plane & (CHANS - 1);
    const int b = plane >> 9;
    const int xi = c >> 7;                 // which of x1..x4
    const float* src = (xi == 0) ? x1 : (xi == 1) ? x2 : (xi == 2) ? x3 : x4;
    src += (size_t)(b * 128 + (c & 127)) * PLANE_SZ;

    const int tid = threadIdx.x;
    const f32x4* p4 = (const f32x4*)src;
    float s = 0.f;
    #pragma unroll
    for (int j = 0; j < 4; ++j) {
        f32x4 v = p4[tid + j * 256];
        s += (v.x + v.y) + (v.z + v.w);
    }
    // wave (64-lane) reduce
    #pragma unroll
    for (int off = 32; off > 0; off >>= 1)
        s += __shfl_down(s, off, 64);

    __shared__ float wsum[4];
    const int lane = tid & 63, wv = tid >> 6;
    if (lane == 0) wsum[wv] = s;
    __syncthreads();
    if (tid == 0) {
        float t = (wsum[0] + wsum[1]) + (wsum[2] + wsum[3]);
        gp[plane] = t * (1.0f / PLANE_SZ);
    }
}

// ---------------------------------------------------------------------------
// Kernel 2 (fused gate + scale): each block owns one (b,c) plane.
//  - issues the 16 KB plane load first (hides latency under gate math)
//  - computes gate[b,c] inline from gp[b, c-32 .. c+32] (uniform, L2-resident)
//  - scales and stores NON-TEMPORALLY so the 134 MB output stream does not
//    evict the input from L3 (input re-read should be an Infinity-Cache hit)
// ---------------------------------------------------------------------------
__global__ __launch_bounds__(256) void gate_scale_kernel(
    const float* __restrict__ x1, const float* __restrict__ x2,
    const float* __restrict__ x3, const float* __restrict__ x4,
    const float* __restrict__ gp,
    const float* __restrict__ conv_w, const float* __restrict__ conv_b,
    const float* __restrict__ lin_w,  const float* __restrict__ lin_b,
    float* __restrict__ out)
{
    const int plane = blockIdx.x;
    const int c = plane & (CHANS - 1);
    const int b = plane >> 9;
    const int xi = c >> 7;
    const float* src = (xi == 0) ? x1 : (xi == 1) ? x2 : (xi == 2) ? x3 : x4;
    src += (size_t)(b * 128 + (c & 127)) * PLANE_SZ;

    const int tid = threadIdx.x;
    const f32x4* p4 = (const f32x4*)src;

    // issue plane loads early
    f32x4 v0 = p4[tid];
    f32x4 v1 = p4[tid + 256];
    f32x4 v2 = p4[tid + 512];
    f32x4 v3 = p4[tid + 768];

    // gate (wave-uniform; taps at c + d*(k-4), d = 1,2,4,8; padding keeps len 512)
    const float* g = gp + b * CHANS;
    float lin = lin_b[0];
    #pragma unroll
    for (int i = 0; i < 4; ++i) {
        const int d = 1 << i;
        float acc = conv_b[i];
        #pragma unroll
        for (int k = 0; k < 9; ++k) {
            const int t = c + d * (k - 4);
            if (t >= 0 && t < CHANS) acc += conv_w[i * 9 + k] * g[t];
        }
        lin += lin_w[i] * fmaxf(acc, 0.f);
    }
    const float gv = 1.0f / (1.0f + expf(-lin));

    f32x4* o4 = (f32x4*)(out + (size_t)plane * PLANE_SZ);
    v0 *= gv; v1 *= gv; v2 *= gv; v3 *= gv;
    __builtin_nontemporal_store(v0, &o4[tid]);
    __builtin_nontemporal_store(v1, &o4[tid + 256]);
    __builtin_nontemporal_store(v2, &o4[tid + 512]);
    __builtin_nontemporal_store(v3, &o4[tid + 768]);
}

extern "C" void kernel_launch(void* const* d_in, const int* in_sizes, int n_in,
                              void* d_out, int out_size, void* d_ws, size_t ws_size,
                              hipStream_t stream) {
    const float* x1     = (const float*)d_in[0];
    const float* x2     = (const float*)d_in[1];
    const float* x3     = (const float*)d_in[2];
    const float* x4     = (const float*)d_in[3];
    const float* conv_w = (const float*)d_in[4];
    const float* conv_b = (const float*)d_in[5];
    const float* lin_w  = (const float*)d_in[6];
    const float* lin_b  = (const float*)d_in[7];
    float* out = (float*)d_out;

    float* gp = (float*)d_ws;              // PLANES floats

    gp_reduce_kernel<<<PLANES, 256, 0, stream>>>(x1, x2, x3, x4, gp);
    gate_scale_kernel<<<PLANES, 256, 0, stream>>>(x1, x2, x3, x4, gp,
                                                  conv_w, conv_b, lin_w, lin_b, out);
}